// Round 3
// baseline (255.694 us; speedup 1.0000x reference)
//
#include <hip/hip_runtime.h>
#include <hip/hip_bf16.h>

typedef __attribute__((ext_vector_type(8))) short short8;
typedef __attribute__((ext_vector_type(4))) short short4v;
typedef __attribute__((ext_vector_type(4))) float f32x4;
typedef __attribute__((ext_vector_type(2))) float f32x2;

__device__ __forceinline__ unsigned short f2bf(float f) {
    unsigned int u = __builtin_bit_cast(unsigned int, f);
    u += 0x7fffu + ((u >> 16) & 1u);   // round-to-nearest-even
    return (unsigned short)(u >> 16);
}

__device__ __forceinline__ short4v cvt4(float a, float b, float c, float d) {
    union { __hip_bfloat162 h[2]; short4v s; } u;
    u.h[0] = __float22bfloat162_rn(make_float2(a, b));
    u.h[1] = __float22bfloat162_rn(make_float2(c, d));
    return u.s;
}

// ---------------------------------------------------------------------------
// Kernel A: partial adjacency sums over 60-frame chunks.
// grid (5, 32), 256 thr.  At_part[(n*5+tc)*625+p] = sum_{60 frames} exp(-2*d2)
// ---------------------------------------------------------------------------
__global__ void kA(const float* __restrict__ xx, float* __restrict__ At_part) {
    __shared__ float xs3[3][60][25];
    const int tc = blockIdx.x, n = blockIdx.y;
    const int tid = threadIdx.x;
    const float* base = xx + (size_t)n * 22500 + tc * 1500;
    for (int idx = tid; idx < 4500; idx += 256) {
        int ch = idx / 1500, rt = idx % 1500;
        xs3[ch][rt / 25][rt % 25] = base[ch * 7500 + rt];
    }
    __syncthreads();
    for (int p = tid; p < 625; p += 256) {
        int v = p / 25, u = p % 25;
        float s = 0.f;
        for (int t = 0; t < 60; ++t) {
            float dx = xs3[0][t][v] - xs3[0][t][u];
            float dy = xs3[1][t][v] - xs3[1][t][u];
            float dz = xs3[2][t][v] - xs3[2][t][u];
            s += __expf(-2.f * (dx * dx + dy * dy + dz * dz));
        }
        At_part[(size_t)(n * 5 + tc) * 625 + p] = s;
    }
}

// ---------------------------------------------------------------------------
// Kernel B1: per-sample reduce + symmetric normalization.  grid 32.
// ---------------------------------------------------------------------------
__global__ void kB1(const float* __restrict__ At_part, float* __restrict__ Acontrib) {
    __shared__ float At[625];
    __shared__ float dinv[25];
    const int n = blockIdx.x, tid = threadIdx.x;
    for (int p = tid; p < 625; p += 256) {
        float s = 0.f;
        for (int tc = 0; tc < 5; ++tc) s += At_part[(size_t)(n * 5 + tc) * 625 + p];
        At[p] = s;
    }
    __syncthreads();
    if (tid < 25) {
        float d = 0.f;
        for (int u = 0; u < 25; ++u) d += At[tid * 25 + u];
        dinv[tid] = rsqrtf(d * (1.f / 300.f));
    }
    __syncthreads();
    for (int p = tid; p < 625; p += 256)
        Acontrib[n * 625 + p] = At[p] * (1.f / 300.f) * dinv[p / 25] * dinv[p % 25] * (1.f / 32.f);
}

// ---------------------------------------------------------------------------
// Kernel B2: block 0 -> bsTg (bf16 [64][72], zero-padded) + fused bias;
//            blocks 1..36 -> W'' = W * bn_scale (bf16, float4-vectorized).
// ---------------------------------------------------------------------------
__global__ void kB2(const float* __restrict__ Acontrib, const float* __restrict__ A_res,
                    const float* __restrict__ W, const float* __restrict__ b,
                    const float* __restrict__ gamma, const float* __restrict__ beta,
                    const float* __restrict__ rm, const float* __restrict__ rv,
                    short* __restrict__ bsTg, short* __restrict__ Wpg,
                    float* __restrict__ bbg) {
    const int tid = threadIdx.x;
    if (blockIdx.x == 0) {
        __shared__ float macc[625];
        for (int p = tid; p < 625; p += 256) {
            float s = 0.f;
            for (int n = 0; n < 32; ++n) s += Acontrib[n * 625 + p];
            macc[p] = s;
        }
        __syncthreads();
        for (int idx = tid; idx < 64 * 72; idx += 256) {
            int col = idx / 72, u = idx % 72;
            float v = 0.f;
            if (col < 50 && u < 50) v = macc[(col % 25) * 25 + (u % 25)] + A_res[col * 50 + u];
            bsTg[idx] = (short)f2bf(v);
        }
        if (tid < 192) {
            float sc = gamma[tid] * rsqrtf(rv[tid] + 1e-5f);
            bbg[tid] = b[tid] * sc + beta[tid] - rm[tid] * sc;
        }
    } else {
        const int e = (blockIdx.x - 1) * 1024 + tid * 4;   // 36*1024 = 36864 exact
        const int o = e / 192;
        const float sc = gamma[o] * rsqrtf(rv[o] + 1e-5f);
        float4 w = *(const float4*)(W + e);
        short4v s4 = { (short)f2bf(w.x * sc), (short)f2bf(w.y * sc),
                       (short)f2bf(w.z * sc), (short)f2bf(w.w * sc) };
        *(short4v*)(Wpg + e) = s4;
    }
}

// ---------------------------------------------------------------------------
// Kernel C: fused graph-conv + 1x1 conv + BN + ReLU.
// grid (75, 32), 256 thr = 4 waves, 4 timesteps per block.
// GEMM1 A-fragments load DIRECTLY from global (u-contiguous, L1/L2-cached);
// only a2T (double-buffered, 20 KB) lives in LDS -> 4 blocks/CU.
// u>=50 pad handled by A_scale's zero K-pad (0 * finite = 0); only an
// address clamp at the buffer end is needed.
// ---------------------------------------------------------------------------
__global__ __launch_bounds__(256, 4)
void kC(const float* __restrict__ x, const short* __restrict__ Wpg,
        const short* __restrict__ bsTg, const float* __restrict__ bbg,
        float* __restrict__ out) {
    __shared__ __align__(16) short a2T[2][25][200];   // 20000 B
    __shared__ float bbs[192];

    const int tid = threadIdx.x;
    const int lane = tid & 63;
    const int wid = tid >> 6;
    const int lam = lane & 15;
    const int kc = (lane >> 4) * 8;
    const int cb = (lane >> 4) * 4;
    const int n = blockIdx.y;
    const int t0 = blockIdx.x * 4;

    // W'' fragments in registers: wave owns output rows [wid*48, wid*48+48)
    const int r0 = wid * 48 + lam;
    short8 wf[3][6];
#pragma unroll
    for (int mt = 0; mt < 3; ++mt)
#pragma unroll
        for (int ks = 0; ks < 6; ++ks)
            wf[mt][ks] = *(const short8*)(Wpg + (r0 + mt * 16) * 192 + ks * 32 + kc);

    // A_scale (GEMM1 B) fragments in registers
    const int ncol = wid * 16 + lam;                  // agg column 0..63 (valid <50)
    const short8 bq0 = *(const short8*)(bsTg + ncol * 72 + kc);
    const short8 bq1 = *(const short8*)(bsTg + ncol * 72 + 32 + kc);

    if (tid < 192) bbs[tid] = bbg[tid];

    const int gbase = n * 1440000 + t0 * 50;
    const int s = ncol >= 25 ? 1 : 0;
    const int vs = ncol - 25 * s;
    const f32x4 z = {0.f, 0.f, 0.f, 0.f};
    const int LIM = 46080000 - 2;

#pragma unroll 1
    for (int tl = 0; tl < 4; ++tl) {
        short* a2w = &a2T[tl & 1][0][0];
        // ---- GEMM1: agg(96x50) for timestep t0+tl, A direct from global ----
#pragma unroll
        for (int mt = 0; mt < 6; ++mt) {
            const int c = mt * 16 + lam;
            const int off0 = gbase + c * 15000 + tl * 50 + kc;
            f32x2 a0 = *(const f32x2*)(x + off0);
            f32x2 a1 = *(const f32x2*)(x + off0 + 2);
            f32x2 a2 = *(const f32x2*)(x + off0 + 4);
            f32x2 a3 = *(const f32x2*)(x + off0 + 6);
            const int off1 = off0 + 32;
            f32x2 b0 = *(const f32x2*)(x + min(off1, LIM));
            f32x2 b1 = *(const f32x2*)(x + min(off1 + 2, LIM));
            f32x2 b2 = *(const f32x2*)(x + min(off1 + 4, LIM));
            f32x2 b3 = *(const f32x2*)(x + min(off1 + 6, LIM));
            union { short4v h[2]; short8 v; } A0, A1;
            A0.h[0] = cvt4(a0.x, a0.y, a1.x, a1.y);
            A0.h[1] = cvt4(a2.x, a2.y, a3.x, a3.y);
            A1.h[0] = cvt4(b0.x, b0.y, b1.x, b1.y);
            A1.h[1] = cvt4(b2.x, b2.y, b3.x, b3.y);
            f32x4 acc1 = z;
            acc1 = __builtin_amdgcn_mfma_f32_16x16x32_bf16(A0.v, bq0, acc1, 0, 0, 0);
            acc1 = __builtin_amdgcn_mfma_f32_16x16x32_bf16(A1.v, bq1, acc1, 0, 0, 0);
            if (ncol < 50)
                *(short4v*)(a2w + vs * 200 + s * 96 + mt * 16 + cb) =
                    cvt4(acc1[0], acc1[1], acc1[2], acc1[3]);
        }
        __syncthreads();

        // ---- GEMM2: out(192x25) for this timestep ----
        f32x4 acc[3][2];
#pragma unroll
        for (int mt = 0; mt < 3; ++mt) { acc[mt][0] = z; acc[mt][1] = z; }
        const int c1 = (16 + lam) < 25 ? (16 + lam) : 24;   // clamp pad cols
#pragma unroll
        for (int ks = 0; ks < 6; ++ks) {
            const short8 B0 = *(const short8*)(a2w + lam * 200 + ks * 32 + kc);
            const short8 B1 = *(const short8*)(a2w + c1 * 200 + ks * 32 + kc);
#pragma unroll
            for (int mt = 0; mt < 3; ++mt) {
                acc[mt][0] = __builtin_amdgcn_mfma_f32_16x16x32_bf16(wf[mt][ks], B0, acc[mt][0], 0, 0, 0);
                acc[mt][1] = __builtin_amdgcn_mfma_f32_16x16x32_bf16(wf[mt][ks], B1, acc[mt][1], 0, 0, 0);
            }
        }
        const int t = t0 + tl;
#pragma unroll
        for (int nt = 0; nt < 2; ++nt) {
            const int col = nt * 16 + lam;
            if (col < 25) {
#pragma unroll
                for (int mt = 0; mt < 3; ++mt) {
                    const int ob = wid * 48 + mt * 16 + cb;
                    float* op = out + ((size_t)(n * 192 + ob) * 300 + t) * 25 + col;
#pragma unroll
                    for (int r = 0; r < 4; ++r) {
                        float v = acc[mt][nt][r] + bbs[ob + r];
                        op[(size_t)r * 7500] = v > 0.f ? v : 0.f;
                    }
                }
            }
        }
        // no trailing barrier: a2T is double-buffered; the barrier after the
        // next GEMM1 orders GEMM2(tl) reads before GEMM1(tl+2) overwrites.
    }
}

// ---------------------------------------------------------------------------
extern "C" void kernel_launch(void* const* d_in, const int* in_sizes, int n_in,
                              void* d_out, int out_size, void* d_ws, size_t ws_size,
                              hipStream_t stream) {
    const float* x     = (const float*)d_in[0];
    const float* xx    = (const float*)d_in[1];
    const float* A_res = (const float*)d_in[2];
    const float* W     = (const float*)d_in[3];
    const float* b     = (const float*)d_in[4];
    const float* gamma = (const float*)d_in[5];
    const float* beta  = (const float*)d_in[6];
    const float* rm    = (const float*)d_in[7];
    const float* rv    = (const float*)d_in[8];
    float* out = (float*)d_out;

    char* ws = (char*)d_ws;
    float* At_part  = (float*)ws;                    // 160*625*4 = 400000 B
    float* Acontrib = (float*)(ws + 400000);         // 32*625*4  =  80000 B
    short* bsTg     = (short*)(ws + 480000);         // 64*72*2   =   9216 B
    short* Wpg      = (short*)(ws + 489216);         // 192*192*2 =  73728 B
    float* bbg      = (float*)(ws + 562944);         // 192*4     =    768 B

    kA<<<dim3(5, 32), 256, 0, stream>>>(xx, At_part);
    kB1<<<32, 256, 0, stream>>>(At_part, Acontrib);
    kB2<<<37, 256, 0, stream>>>(Acontrib, A_res, W, b, gamma, beta, rm, rv, bsTg, Wpg, bbg);
    kC<<<dim3(75, 32), 256, 0, stream>>>(x, Wpg, bsTg, bbg, out);
}

// Round 4
// 194.792 us; speedup vs baseline: 1.3127x; 1.3127x over previous
//
#include <hip/hip_runtime.h>
#include <hip/hip_bf16.h>

typedef __attribute__((ext_vector_type(8))) short short8;
typedef __attribute__((ext_vector_type(4))) short short4v;
typedef __attribute__((ext_vector_type(4))) float f32x4;

__device__ __forceinline__ unsigned short f2bf(float f) {
    unsigned int u = __builtin_bit_cast(unsigned int, f);
    u += 0x7fffu + ((u >> 16) & 1u);   // round-to-nearest-even
    return (unsigned short)(u >> 16);
}
__device__ __forceinline__ unsigned int pack2(float a, float b) {
    union { __hip_bfloat162 h; unsigned int u; } r;
    r.h = __float22bfloat162_rn(make_float2(a, b));
    return r.u;
}
__device__ __forceinline__ short4v cvt4(float a, float b, float c, float d) {
    union { __hip_bfloat162 h[2]; short4v s; } u;
    u.h[0] = __float22bfloat162_rn(make_float2(a, b));
    u.h[1] = __float22bfloat162_rn(make_float2(c, d));
    return u.s;
}

// ---------------------------------------------------------------------------
// Kernel A: partial adjacency sums over 60-frame chunks.
// grid (5, 32), 256 thr.  At_part[(n*5+tc)*625+p] = sum_{60 frames} exp(-2*d2)
// ---------------------------------------------------------------------------
__global__ void kA(const float* __restrict__ xx, float* __restrict__ At_part) {
    __shared__ float xs3[3][60][25];
    const int tc = blockIdx.x, n = blockIdx.y;
    const int tid = threadIdx.x;
    const float* base = xx + (size_t)n * 22500 + tc * 1500;
    for (int idx = tid; idx < 4500; idx += 256) {
        int ch = idx / 1500, rt = idx % 1500;
        xs3[ch][rt / 25][rt % 25] = base[ch * 7500 + rt];
    }
    __syncthreads();
    for (int p = tid; p < 625; p += 256) {
        int v = p / 25, u = p % 25;
        float s = 0.f;
        for (int t = 0; t < 60; ++t) {
            float dx = xs3[0][t][v] - xs3[0][t][u];
            float dy = xs3[1][t][v] - xs3[1][t][u];
            float dz = xs3[2][t][v] - xs3[2][t][u];
            s += __expf(-2.f * (dx * dx + dy * dy + dz * dz));
        }
        At_part[(size_t)(n * 5 + tc) * 625 + p] = s;
    }
}

// ---------------------------------------------------------------------------
// Kernel B1: per-sample reduce + symmetric normalization.  grid 32.
// ---------------------------------------------------------------------------
__global__ void kB1(const float* __restrict__ At_part, float* __restrict__ Acontrib) {
    __shared__ float At[625];
    __shared__ float dinv[25];
    const int n = blockIdx.x, tid = threadIdx.x;
    for (int p = tid; p < 625; p += 256) {
        float s = 0.f;
        for (int tc = 0; tc < 5; ++tc) s += At_part[(size_t)(n * 5 + tc) * 625 + p];
        At[p] = s;
    }
    __syncthreads();
    if (tid < 25) {
        float d = 0.f;
        for (int u = 0; u < 25; ++u) d += At[tid * 25 + u];
        dinv[tid] = rsqrtf(d * (1.f / 300.f));
    }
    __syncthreads();
    for (int p = tid; p < 625; p += 256)
        Acontrib[n * 625 + p] = At[p] * (1.f / 300.f) * dinv[p / 25] * dinv[p % 25] * (1.f / 32.f);
}

// ---------------------------------------------------------------------------
// Kernel B2: block 0 -> bsTg (bf16 [64][72], zero-padded) + fused bias;
//            blocks 1..36 -> W'' = W * bn_scale (bf16, float4-vectorized).
// ---------------------------------------------------------------------------
__global__ void kB2(const float* __restrict__ Acontrib, const float* __restrict__ A_res,
                    const float* __restrict__ W, const float* __restrict__ b,
                    const float* __restrict__ gamma, const float* __restrict__ beta,
                    const float* __restrict__ rm, const float* __restrict__ rv,
                    short* __restrict__ bsTg, short* __restrict__ Wpg,
                    float* __restrict__ bbg) {
    const int tid = threadIdx.x;
    if (blockIdx.x == 0) {
        __shared__ float macc[625];
        for (int p = tid; p < 625; p += 256) {
            float s = 0.f;
            for (int n = 0; n < 32; ++n) s += Acontrib[n * 625 + p];
            macc[p] = s;
        }
        __syncthreads();
        for (int idx = tid; idx < 64 * 72; idx += 256) {
            int col = idx / 72, u = idx % 72;
            float v = 0.f;
            if (col < 50 && u < 50) v = macc[(col % 25) * 25 + (u % 25)] + A_res[col * 50 + u];
            bsTg[idx] = (short)f2bf(v);
        }
        if (tid < 192) {
            float sc = gamma[tid] * rsqrtf(rv[tid] + 1e-5f);
            bbg[tid] = b[tid] * sc + beta[tid] - rm[tid] * sc;
        }
    } else {
        const int e = (blockIdx.x - 1) * 1024 + tid * 4;   // 36*1024 = 36864 exact
        const int o = e / 192;
        const float sc = gamma[o] * rsqrtf(rv[o] + 1e-5f);
        float4 w = *(const float4*)(W + e);
        short4v s4 = { (short)f2bf(w.x * sc), (short)f2bf(w.y * sc),
                       (short)f2bf(w.z * sc), (short)f2bf(w.w * sc) };
        *(short4v*)(Wpg + e) = s4;
    }
}

// ---------------------------------------------------------------------------
// Kernel C: fused graph-conv + 1x1 conv + BN + ReLU.
// grid (150, 32), 256 thr = 4 waves, 2 timesteps per block.
// LDS: xs [2][96][64] bf16 swizzled (24.6 KB) + a2T [25][200] (10 KB)
//      + bias  => 35.3 KB => 4 blocks/CU.
// ---------------------------------------------------------------------------
__global__ __launch_bounds__(256, 4)
void kC(const float* __restrict__ x, const short* __restrict__ Wpg,
        const short* __restrict__ bsTg, const float* __restrict__ bbg,
        float* __restrict__ out) {
    __shared__ __align__(16) char xsb[2 * 96 * 128];   // 24576 B
    __shared__ __align__(16) short a2T[25][200];       // 10000 B
    __shared__ float bbs[192];

    const int tid = threadIdx.x;
    const int lane = tid & 63;
    const int wid = tid >> 6;
    const int lam = lane & 15;
    const int kc = (lane >> 4) * 8;    // K-offset within fragment (elems)
    const int cb = (lane >> 4) * 4;    // C/D row sub-block
    const int n = blockIdx.y;
    const int t0 = blockIdx.x * 2;

    // W'' fragments: wave owns output rows [wid*48, wid*48+48)
    const int r0 = wid * 48 + lam;
    short8 wf[3][6];
#pragma unroll
    for (int mt = 0; mt < 3; ++mt)
#pragma unroll
        for (int ks = 0; ks < 6; ++ks)
            wf[mt][ks] = *(const short8*)(Wpg + (r0 + mt * 16) * 192 + ks * 32 + kc);

    // A_scale (GEMM1 B) fragments in registers
    const int ncol = wid * 16 + lam;                   // agg column 0..63 (valid<50)
    const short8 bq0 = *(const short8*)(bsTg + ncol * 72 + kc);
    const short8 bq1 = *(const short8*)(bsTg + ncol * 72 + 32 + kc);

    if (tid < 192) bbs[tid] = bbg[tid];

    // ---- stage x: 96 rows x 100 contiguous floats, float4 loads ----
    const float* xbase = x + (size_t)n * 1440000 + (size_t)t0 * 50;
    for (int idx = tid; idx < 2400; idx += 256) {
        int c = idx / 25, q = idx - c * 25;            // 25 float4 per row of 100
        float4 v = *(const float4*)(xbase + (size_t)c * 15000 + 4 * q);
        int g = 4 * q;                                 // 0..96; pairs never straddle tl
        int tl0 = g / 50,       u0 = g - 50 * tl0;
        int tl1 = (g + 2) / 50, u1 = (g + 2) - 50 * tl1;
        int swz = (c & 7) << 4;
        *(unsigned int*)(xsb + ((tl0 * 12288 + c * 128 + u0 * 2) ^ swz)) = pack2(v.x, v.y);
        *(unsigned int*)(xsb + ((tl1 * 12288 + c * 128 + u1 * 2) ^ swz)) = pack2(v.z, v.w);
    }
    // zero the u=50..63 pad (must be finite: pad * A_scale-zero must be 0)
    for (int idx = tid; idx < 1344; idx += 256) {
        int r = idx / 7, k = idx - r * 7;
        int tl = r / 96, c = r - 96 * tl;
        *(unsigned int*)(xsb + ((tl * 12288 + c * 128 + (50 + 2 * k) * 2) ^ ((c & 7) << 4))) = 0;
    }
    __syncthreads();

    const f32x4 z = {0.f, 0.f, 0.f, 0.f};
    const int s = ncol >= 25 ? 1 : 0;
    const int vs = ncol - 25 * s;

#pragma unroll 1
    for (int tl = 0; tl < 2; ++tl) {
        // ---- GEMM1: agg(96x50) for timestep t0+tl ----
        f32x4 acc1[6];
#pragma unroll
        for (int mt = 0; mt < 6; ++mt) acc1[mt] = z;
#pragma unroll
        for (int ks = 0; ks < 2; ++ks) {
#pragma unroll
            for (int mt = 0; mt < 6; ++mt) {
                int c = mt * 16 + lam;
                const short8 afr = *(const short8*)(xsb +
                    ((tl * 12288 + c * 128 + (ks * 32 + kc) * 2) ^ ((c & 7) << 4)));
                acc1[mt] = __builtin_amdgcn_mfma_f32_16x16x32_bf16(
                    afr, ks ? bq1 : bq0, acc1[mt], 0, 0, 0);
            }
        }
        if (ncol < 50) {
#pragma unroll
            for (int mt = 0; mt < 6; ++mt)
                *(short4v*)(&a2T[vs][s * 96 + mt * 16 + cb]) =
                    cvt4(acc1[mt][0], acc1[mt][1], acc1[mt][2], acc1[mt][3]);
        }
        __syncthreads();

        // ---- GEMM2: out(192x25) for this timestep ----
        f32x4 acc[3][2];
#pragma unroll
        for (int mt = 0; mt < 3; ++mt) { acc[mt][0] = z; acc[mt][1] = z; }
        const int c1 = (16 + lam) < 25 ? (16 + lam) : 24;   // clamp pad cols
#pragma unroll
        for (int ks = 0; ks < 6; ++ks) {
            const short8 B0 = *(const short8*)(&a2T[lam][ks * 32 + kc]);
            const short8 B1 = *(const short8*)(&a2T[c1][ks * 32 + kc]);
#pragma unroll
            for (int mt = 0; mt < 3; ++mt) {
                acc[mt][0] = __builtin_amdgcn_mfma_f32_16x16x32_bf16(wf[mt][ks], B0, acc[mt][0], 0, 0, 0);
                acc[mt][1] = __builtin_amdgcn_mfma_f32_16x16x32_bf16(wf[mt][ks], B1, acc[mt][1], 0, 0, 0);
            }
        }
        const int t = t0 + tl;
#pragma unroll
        for (int nt = 0; nt < 2; ++nt) {
            const int col = nt * 16 + lam;
            if (col < 25) {
#pragma unroll
                for (int mt = 0; mt < 3; ++mt) {
                    const int ob = wid * 48 + mt * 16 + cb;
                    float* op = out + ((size_t)(n * 192 + ob) * 300 + t) * 25 + col;
#pragma unroll
                    for (int r = 0; r < 4; ++r) {
                        float v = acc[mt][nt][r] + bbs[ob + r];
                        op[(size_t)r * 7500] = v > 0.f ? v : 0.f;
                    }
                }
            }
        }
        if (tl == 0) __syncthreads();   // WAR on a2T before next GEMM1 write
    }
}

// ---------------------------------------------------------------------------
extern "C" void kernel_launch(void* const* d_in, const int* in_sizes, int n_in,
                              void* d_out, int out_size, void* d_ws, size_t ws_size,
                              hipStream_t stream) {
    const float* x     = (const float*)d_in[0];
    const float* xx    = (const float*)d_in[1];
    const float* A_res = (const float*)d_in[2];
    const float* W     = (const float*)d_in[3];
    const float* b     = (const float*)d_in[4];
    const float* gamma = (const float*)d_in[5];
    const float* beta  = (const float*)d_in[6];
    const float* rm    = (const float*)d_in[7];
    const float* rv    = (const float*)d_in[8];
    float* out = (float*)d_out;

    char* ws = (char*)d_ws;
    float* At_part  = (float*)ws;                    // 160*625*4 = 400000 B
    float* Acontrib = (float*)(ws + 400000);         // 32*625*4  =  80000 B
    short* bsTg     = (short*)(ws + 480000);         // 64*72*2   =   9216 B
    short* Wpg      = (short*)(ws + 489216);         // 192*192*2 =  73728 B
    float* bbg      = (float*)(ws + 562944);         // 192*4     =    768 B

    kA<<<dim3(5, 32), 256, 0, stream>>>(xx, At_part);
    kB1<<<32, 256, 0, stream>>>(At_part, Acontrib);
    kB2<<<37, 256, 0, stream>>>(Acontrib, A_res, W, b, gamma, beta, rm, rv, bsTg, Wpg, bbg);
    kC<<<dim3(150, 32), 256, 0, stream>>>(x, Wpg, bsTg, bbg, out);
}